// Round 1
// baseline (229.871 us; speedup 1.0000x reference)
//
#include <hip/hip_runtime.h>
#include <math.h>

// VectorQuantizer: x (32768,64) f32, codebook (8192,64) f32, start/end/use_sk ints.
// Outputs concat: x_q_st (2097152 f32) | loss (1 f32) | indices (32768 as f32 values).
//
// R10: mask-free two-pass. Pass1 emits ONLY per-chunk f16 minima of the bf16 filter
// metric g(k) = -2*dot_bf(x,c_k); rescue exactly re-evaluates ALL 32 codes of every
// flagged chunk (chunks with mv <= global_min + WINDOW) with the BIT-EXACT R1
// numpy-replica arithmetic.
//  vq_sc:    sc_k exact (pairwise-8 numpy replica, f32) + cb -> bf16 rows (K=64,
//            no padding: the sc fold is DROPPED from the filter; sc_max <= 64*(1/8192)^2
//            = 9.6e-7, charged against the window budget: 2*err_bf + sc_max + f16 ulps
//            = 1.6e-4 + ~5e-6 < WINDOW=3e-4).
//  vq_pass1: 32x32x16 MFMA, block = 256 tokens x 2048 codes (16 iters of 128), K=64
//            (4 ks steps, was 5 with the K=80 pad: -20% MFMA). No Xs tile: B-frags
//            loaded straight from global with inline f32->bf16. Cs stride 72 ushorts
//            (36 dwords == 4 mod 8: conflict-free b128 walk). Per-chunk f16 minima
//            accumulate in LDS (minL[256][72]) -- NO global stores inside the K-loop
//            (the old per-nb scattered uint2/uint4 stores inflated WRITE_SIZE to
//            175MB and drained into every barrier's vmcnt(0)) -- one fully-coalesced
//            16MB flush at the end.
//  vq_rescue: wave/token. Butterfly min over f16 minima -> thr = m + WINDOW; for each
//            flagged chunk, lanes 0..31 (x2 chunks concurrently when >=2 flagged in a
//            ballot) each evaluate one code from global cb with the BIT-EXACT R1
//            arithmetic (pairwise-8, separate mul+add); lex-min (enc(d),k) == strict-<
//            ascending-k first-occurrence.
// Exactness: ref argmin k* satisfies g_bf(k*) <= global chunk-min + 2*err_bf + sc_max
// (R6-validated budget + 9.6e-7 slack < W) -> k*'s chunk is always flagged; rescue
// evaluates EVERY in-range code of flagged chunks exactly -> lex-min over a superset
// containing the reference argmin == reference.
// DO NOT change the exact-path arithmetic: inter-code d gaps are ~1 ulp of d.

#define N_E    8192
#define EDIM   64
#define NTOK   32768
#define NELEM  (NTOK * EDIM)
#define CSZ    32                  // chunk size
#define NCHUNK (N_E / CSZ)         // 256 chunks
#define WINDOW 3e-4f
#define TTOK   256                 // pass-1 tokens per block
#define TCODE  2048                // pass-1 codes per block (16 iters of 128)
#define SROW   72                  // Cs stride (ushorts; 36 dwords == 4 mod 8)
#define MROW   72                  // minL stride (ushorts; 144 B rows, 16B-aligned)

typedef __attribute__((ext_vector_type(8)))  short          short8;
typedef __attribute__((ext_vector_type(8)))  unsigned short ushort8v;
typedef __attribute__((ext_vector_type(16))) float          f32x16;

__device__ __forceinline__ unsigned short f2bf(float f) {   // RTNE f32->bf16 bits
  unsigned int u = __float_as_uint(f);
  return (unsigned short)((u + 0x7FFFu + ((u >> 16) & 1u)) >> 16);
}
__device__ __forceinline__ unsigned short f2h(float f) {
  union { _Float16 h; unsigned short u; } cv; cv.h = (_Float16)f; return cv.u;
}
__device__ __forceinline__ float h2f(unsigned short b) {
  union { _Float16 h; unsigned short u; } cv; cv.u = b; return (float)cv.h;
}
__device__ __forceinline__ float max16(const f32x16 a) {
  float m0 = fmaxf(fmaxf(a[0], a[1]),   fmaxf(a[2], a[3]));
  float m1 = fmaxf(fmaxf(a[4], a[5]),   fmaxf(a[6], a[7]));
  float m2 = fmaxf(fmaxf(a[8], a[9]),   fmaxf(a[10], a[11]));
  float m3 = fmaxf(fmaxf(a[12], a[13]), fmaxf(a[14], a[15]));
  return fmaxf(fmaxf(m0, m1), fmaxf(m2, m3));
}

// ---------------- sc (exact pairwise-8) + cb -> bf16 rows (K=64) --------------------
__global__ __launch_bounds__(256) void vq_sc(const float* __restrict__ cb,
                                             float* __restrict__ sc,
                                             unsigned short* __restrict__ cbf) {
#pragma clang fp contract(off)
  int r = blockIdx.x * 256 + threadIdx.x;
  const float4* c4 = (const float4*)(cb + (size_t)r * EDIM);
  float a[8];
#pragma unroll
  for (int j = 0; j < 8; ++j) a[j] = 0.0f;
#pragma unroll
  for (int i = 0; i < 8; ++i) {
    float4 pA = c4[2*i], pB = c4[2*i+1];
    a[0] += pA.x * pA.x; a[1] += pA.y * pA.y; a[2] += pA.z * pA.z; a[3] += pA.w * pA.w;
    a[4] += pB.x * pB.x; a[5] += pB.y * pB.y; a[6] += pB.z * pB.z; a[7] += pB.w * pB.w;
  }
  float sval = ((a[0]+a[1]) + (a[2]+a[3])) + ((a[4]+a[5]) + (a[6]+a[7]));
  sc[r] = sval;
  unsigned short* dst = cbf + (size_t)r * EDIM;
#pragma unroll
  for (int h = 0; h < 8; ++h) {
    float4 fA = c4[2*h], fB = c4[2*h+1];
    ushort8v o = {f2bf(fA.x), f2bf(fA.y), f2bf(fA.z), f2bf(fA.w),
                  f2bf(fB.x), f2bf(fB.y), f2bf(fB.z), f2bf(fB.w)};
    *(ushort8v*)&dst[h * 8] = o;
  }
}

// ---------------- pass 1: 32x32x16 MFMA filter -> per-chunk f16 minima --------------
// Frags: A[m=lane&31][k=8*(lane>>5)+j] (codes), B same (tokens),
// D: col=lane&31 (token), row=(reg&3)+8*(reg>>2)+4*(lane>>5) (code).
__global__ __launch_bounds__(256, 2) void vq_pass1(
    const float* __restrict__ x, const unsigned short* __restrict__ cbf,
    unsigned short* __restrict__ minima,
    const int* __restrict__ p_start, const int* __restrict__ p_end) {
  __shared__ unsigned short Cs[128 * SROW];     // 18432 B
  __shared__ unsigned short minL[TTOK * MROW];  // 36864 B
  int tid = threadIdx.x;
  int tb = blockIdx.x;    // token split [0,128)
  int cbk = blockIdx.y;   // code split  [0,4)
  int s = *p_start, e = *p_end;

  int lane = tid & 63, wv = tid >> 6;
  int half = lane >> 5, ln = lane & 31;
  int tokbase = wv * 64;

  // ---- stage first code tile: 128 rows x 8 ushort8 (linear, coalesced) ----
  const ushort8v* cg0 = (const ushort8v*)(cbf + (size_t)cbk * TCODE * EDIM);
#pragma unroll
  for (int p = 0; p < 4; ++p) {
    int idx = tid + p * 256;
    int row = idx >> 3, h = idx & 7;
    *(ushort8v*)&Cs[row * SROW + h * 8] = cg0[idx];
  }

  // ---- B fragments straight from global (fused f32 -> bf16), no LDS round-trip ----
  short8 bfr[2][4];
#pragma unroll
  for (int tg = 0; tg < 2; ++tg) {
    const float* xrow =
        x + (size_t)(tb * TTOK + tokbase + tg * 32 + ln) * EDIM + half * 8;
#pragma unroll
    for (int ks = 0; ks < 4; ++ks) {
      float4 fA = *(const float4*)(xrow + ks * 16);
      float4 fB = *(const float4*)(xrow + ks * 16 + 4);
      short8 v = {(short)f2bf(fA.x), (short)f2bf(fA.y), (short)f2bf(fA.z),
                  (short)f2bf(fA.w), (short)f2bf(fB.x), (short)f2bf(fB.y),
                  (short)f2bf(fB.z), (short)f2bf(fB.w)};
      bfr[tg][ks] = v;
    }
  }
  __syncthreads();

  for (int nb = 0; nb < 16; ++nb) {
    ushort8v creg[4];
    if (nb < 15) {                               // prefetch next tile into registers
      const ushort8v* cg =
          (const ushort8v*)(cbf + ((size_t)cbk * TCODE + (nb + 1) * 128) * EDIM);
#pragma unroll
      for (int p = 0; p < 4; ++p) creg[p] = cg[tid + p * 256];
    }
    f32x16 acc[2][4];
#pragma unroll
    for (int tg = 0; tg < 2; ++tg)
#pragma unroll
      for (int ct = 0; ct < 4; ++ct) acc[tg][ct] = (f32x16)0.0f;
#pragma unroll
    for (int ks = 0; ks < 4; ++ks)
#pragma unroll
      for (int ct = 0; ct < 4; ++ct) {
        short8 a = *(const short8*)&Cs[(ct*32 + ln) * SROW + ks*16 + half*8];
        acc[0][ct] = __builtin_amdgcn_mfma_f32_32x32x16_bf16(a, bfr[0][ks],
                                                             acc[0][ct], 0, 0, 0);
        acc[1][ct] = __builtin_amdgcn_mfma_f32_32x32x16_bf16(a, bfr[1][ks],
                                                             acc[1][ct], 0, 0, 0);
      }
    __syncthreads();                             // all Cs reads done
    if (nb < 15) {
#pragma unroll
      for (int p = 0; p < 4; ++p) {
        int idx = tid + p * 256;
        int row = idx >> 3, h = idx & 7;
        *(ushort8v*)&Cs[row * SROW + h * 8] = creg[p];
      }
    }
    // epilogue (registers + LDS only; overlaps Cs writes): per-chunk max -> f16 minima
    int cbase0 = cbk * TCODE + nb * 128;
    unsigned int hsel[4];
#pragma unroll
    for (int ct = 0; ct < 4; ++ct) {
      int c0 = cbase0 + ct * 32;
      bool full = (c0 >= s) && (c0 + 32 <= e);
      float v0, v1;
      if (full) {
        v0 = max16(acc[0][ct]);
        v1 = max16(acc[1][ct]);
      } else {
        v0 = -INFINITY; v1 = -INFINITY;
#pragma unroll
        for (int r = 0; r < 16; ++r) {
          int code = c0 + (r & 3) + 8 * (r >> 2) + 4 * half;
          if (code >= s && code < e) {
            v0 = fmaxf(v0, acc[0][ct][r]);
            v1 = fmaxf(v1, acc[1][ct][r]);
          }
        }
      }
      v0 = fmaxf(v0, __shfl_xor(v0, 32, 64));    // chunk max in f32 acc space
      v1 = fmaxf(v1, __shfl_xor(v1, 32, 64));
      float vs = half ? v1 : v0;                 // this thread's own token (tg==half)
      hsel[ct] = (unsigned int)f2h(-2.0f * vs);
    }
    uint2 pk;
    pk.x = hsel[0] | (hsel[1] << 16);
    pk.y = hsel[2] | (hsel[3] << 16);
    *(uint2*)&minL[(unsigned)tid * MROW + nb * 4] = pk;   // token==tid row, 8B write
    __syncthreads();                             // Cs writes visible before next MFMA
  }

  // ---- flush minL -> minima, fully coalesced (full 64B lines, no partial writes) ----
#pragma unroll
  for (int p = 0; p < 8; ++p) {
    int idx = tid + p * 256;                     // 2048 uint4 = 256 tok x 64 chunks
    int tl = idx >> 3, part = idx & 7;
    uint4 v = *(const uint4*)&minL[tl * MROW + part * 8];
    *(uint4*)(minima + ((size_t)(tb * TTOK + tl)) * NCHUNK + cbk * 64 + part * 8) = v;
  }
}

// ---------------- pass 2: flagged-chunk exact rescue + epilogue ----------------------
// Wave per token. For each flagged chunk (mv <= min + WINDOW), lanes 0..31 each
// evaluate one code with the BIT-EXACT R1 numpy-replica arithmetic; two chunks run
// concurrently (lanes 32..63 take the second) when a ballot has >=2 set bits.
__global__ __launch_bounds__(256) void vq_rescue(
    const float* __restrict__ x, const float* __restrict__ cb,
    const float* __restrict__ sc, const unsigned short* __restrict__ minima,
    float* __restrict__ out_xq, float* __restrict__ out_idx,
    float* __restrict__ partial,
    const int* __restrict__ p_start, const int* __restrict__ p_end) {
#pragma clang fp contract(off)
  __shared__ float xs[4][64];
  __shared__ float sdata[4];
  int tid  = threadIdx.x;
  int wv   = tid >> 6;
  int lane = tid & 63;
  int token = blockIdx.x * 4 + wv;

  float xx = x[(size_t)token * EDIM + lane];
  xs[wv][lane] = xx;
  __syncthreads();
  const float4* xl4 = (const float4*)xs[wv];

  // sx = np.sum(x*x) pairwise-8 replica
  float a[8];
#pragma unroll
  for (int j = 0; j < 8; ++j) a[j] = 0.0f;
#pragma unroll
  for (int i = 0; i < 8; ++i) {
    float4 pA = xl4[2*i], pB = xl4[2*i+1];
    a[0] += pA.x * pA.x; a[1] += pA.y * pA.y; a[2] += pA.z * pA.z; a[3] += pA.w * pA.w;
    a[4] += pB.x * pB.x; a[5] += pB.y * pB.y; a[6] += pB.z * pB.z; a[7] += pB.w * pB.w;
  }
  float sx = ((a[0]+a[1]) + (a[2]+a[3])) + ((a[4]+a[5]) + (a[6]+a[7]));

  // minima row: lane covers chunks 4*lane .. 4*lane+3 (coalesced uint2)
  uint2 u2 = *(const uint2*)(minima + (size_t)token * NCHUNK + lane * 4);
  float mv[4] = {h2f((unsigned short)(u2.x & 0xFFFFu)),
                 h2f((unsigned short)(u2.x >> 16)),
                 h2f((unsigned short)(u2.y & 0xFFFFu)),
                 h2f((unsigned short)(u2.y >> 16))};
  float m = fminf(fminf(mv[0], mv[1]), fminf(mv[2], mv[3]));
#pragma unroll
  for (int off = 32; off >= 1; off >>= 1) m = fminf(m, __shfl_xor(m, off, 64));
  float thr = m + WINDOW;

  int s = *p_start, e = *p_end;
  unsigned long long bestpack = ~0ull;
  int ln32 = lane & 31;

#pragma unroll
  for (int cc = 0; cc < 4; ++cc) {
    unsigned long long bal = __ballot(mv[cc] <= thr);
    while (bal) {                                // uniform loop (ballot is wave-wide)
      int l0 = __ffsll(bal) - 1; bal &= bal - 1;
      int l1 = -1;
      if (bal) { l1 = __ffsll(bal) - 1; bal &= bal - 1; }
      int lsel = (lane < 32) ? l0 : l1;
      if (lsel >= 0) {
        int k = (lsel * 4 + cc) * CSZ + ln32;
        if (k >= s && k < e) {
          const float4* c4 = (const float4*)(cb + (size_t)k * EDIM);
          float t[8];
#pragma unroll
          for (int jj = 0; jj < 8; ++jj) t[jj] = 0.0f;
#pragma unroll
          for (int i = 0; i < 8; ++i) {          // elements 8i..8i+7, i ascending
            float4 cA4 = c4[2*i], cB4 = c4[2*i+1];
            float4 pA = xl4[2*i], pB = xl4[2*i+1];
            t[0] += cA4.x * pA.x; t[1] += cA4.y * pA.y;
            t[2] += cA4.z * pA.z; t[3] += cA4.w * pA.w;
            t[4] += cB4.x * pB.x; t[5] += cB4.y * pB.y;
            t[6] += cB4.z * pB.z; t[7] += cB4.w * pB.w;
          }
          float tt = ((t[0]+t[1]) + (t[2]+t[3])) + ((t[4]+t[5]) + (t[6]+t[7]));
          float d = (sx + sc[k]) - 2.0f * tt;
          unsigned int db = __float_as_uint(d);
          unsigned int en = db ^ ((unsigned int)((int)db >> 31) | 0x80000000u);
          unsigned long long pk = ((unsigned long long)en << 32) | (unsigned int)k;
          if (pk < bestpack) bestpack = pk;
        }
      }
    }
  }
  // lex-min reduce: (d asc, k asc) == numpy first-occurrence argmin
#pragma unroll
  for (int off = 32; off >= 1; off >>= 1) {
    unsigned long long o = __shfl_xor(bestpack, off, 64);
    if (o < bestpack) bestpack = o;
  }
  int bidx = (int)(unsigned int)(bestpack & 0xFFFFFFFFull);

  float qv = cb[(size_t)bidx * EDIM + lane];
  float diff = qv - xx;                              // fl(x_q - x)
  out_xq[(size_t)token * EDIM + lane] = xx + diff;   // fl(x + fl(x_q - x))
  if (lane == 0) out_idx[token] = (float)bidx;

  float l = diff * diff;
#pragma unroll
  for (int off = 32; off >= 1; off >>= 1) l += __shfl_down(l, off, 64);
  if (lane == 0) sdata[wv] = l;
  __syncthreads();
  if (tid == 0)
    partial[blockIdx.x] = (sdata[0] + sdata[1]) + (sdata[2] + sdata[3]);
}

// ---------------- final loss reduction ----------------------------------------------
__global__ __launch_bounds__(256) void vq_loss(const float* __restrict__ partial,
                                               float* __restrict__ out_loss) {
  int tid = threadIdx.x;
  float s = 0.0f;
  for (int i = tid; i < NTOK / 4; i += 256) s += partial[i];
#pragma unroll
  for (int off = 32; off >= 1; off >>= 1) s += __shfl_down(s, off, 64);
  __shared__ float sdata[4];
  if ((tid & 63) == 0) sdata[tid >> 6] = s;
  __syncthreads();
  if (tid == 0) {
    float total = (sdata[0] + sdata[1]) + (sdata[2] + sdata[3]);
    float m = total * (1.0f / (float)NELEM);
    out_loss[0] = m + 0.25f * m;
  }
}

// ---------------- launch -------------------------------------------------------------
extern "C" void kernel_launch(void* const* d_in, const int* in_sizes, int n_in,
                              void* d_out, int out_size, void* d_ws, size_t ws_size,
                              hipStream_t stream) {
  const float* x  = (const float*)d_in[0];
  const float* cb = (const float*)d_in[1];
  const int* p_start = (const int*)d_in[2];
  const int* p_end   = (const int*)d_in[3];

  float* ws = (float*)d_ws;
  float* sc      = ws;                                            // 8192 f
  float* partial = ws + N_E;                                      // 8192 f
  unsigned short* cbf    = (unsigned short*)(ws + 2 * N_E);       // 8192*64 us (1MB)
  unsigned short* minima = cbf + (size_t)N_E * EDIM;              // 32768*256 us (16MB)

  float* out      = (float*)d_out;
  float* out_xq   = out;                 // 2097152
  float* out_loss = out + NELEM;         // 1
  float* out_idx  = out + NELEM + 1;     // 32768

  vq_sc<<<N_E / 256, 256, 0, stream>>>(cb, sc, cbf);
  dim3 g1(NTOK / TTOK, N_E / TCODE);
  vq_pass1<<<g1, 256, 0, stream>>>(x, cbf, minima, p_start, p_end);
  vq_rescue<<<NTOK / 4, 256, 0, stream>>>(x, cb, sc, minima, out_xq, out_idx,
                                          partial, p_start, p_end);
  vq_loss<<<1, 256, 0, stream>>>(partial, out_loss);
}